// Round 12
// baseline (237.960 us; speedup 1.0000x reference)
//
#include <hip/hip_runtime.h>

// AdultConnectomeNetwork: 3 layers of xt = A_sp @ (W_sp @ xt) + bias.
// Round 27: de-staged pass1. r26 showed pass1 (46.6us) is serial-chain
// latency-bound (VALUBusy 4.5%, occ 18%, 810 GB/s): each edge paid ~3 LDS
// round-trips (hist atomic, cursor atomic + stage write, re-read) + staged
// store. The staging existed only for write coalescing, but dirty-LINE count
// (the r22/r23 density law's real variable) is identical with direct 8B
// writes: segments stay ~63B contiguous per (block,bin). So:
//   hist -> claim (h[j] = j*BCAP1 + atomicAdd(cursor[j], c): h becomes the
//   GLOBAL slot cursor) -> write (d = atomicAdd(&h[bin],1); e1[d] = edge).
// Prefix scan, hscan, 24KB sKey/sAW staging, readout loop, 2 barriers: gone.
//  - Transpose tile, pass2, spmm, dense chain: bit-identical r26 code.
//  - Within-segment order shifts (claim/issue order) - freedom established
//    (r22 random order, same absmax 2048).
// Hardening: computed indices clamped (logic error -> absmax fail, not fault).

#define NN 50000
#define NNZ_E 1600000
#define NB (NN * 32)
#define CHUNK 3072
#define NBLK1 ((NNZ_E + CHUNK - 1) / CHUNK)      // 521
#define NBIN ((NN + 127) / 128)                  // 391 bins of 128 rows
#define CAP2 5120                                // bin fill cap (mean 4092, +16 sigma)
#define BCAP1 6144                               // e1 window slots per bin
#define LENE (NBIN * BCAP1)                      // 2402304 e1 slots (19.2 MB)
#define BCAP 6144                                // padded kv capacity per bin
#define LENP (NBIN * BCAP)                       // 2402304 padded kv slots
#define TIN_BLKS 196                             // transpose tiles of 256 n

__device__ __forceinline__ int clampi(int v, int hi) {  // [0, hi]
    v = v < 0 ? 0 : v;
    return v > hi ? hi : v;
}

__device__ __forceinline__ unsigned short f2h(float v) {
    union { _Float16 h; unsigned short u; } cv;
    cv.h = (_Float16)v;
    return cv.u;
}

__device__ __forceinline__ float kv_val(unsigned kv) {
    union { unsigned short u; _Float16 h; } cv;
    cv.u = (unsigned short)(kv >> 16);
    return (float)cv.h;
}

// Pass 1 (de-staged): hist -> claim global window segment per nonempty bin
// (h[] becomes global e1 slot cursor) -> direct 8B interleaved writes.
// key = (row<<16)|col. Blocks >= NBLK1 run the LDS-tiled coalesced input
// transpose (fp32 [B,N] -> fp16 [N,32]).
__global__ __launch_bounds__(256) void pass1_kernel(
        const int* __restrict__ row, const int* __restrict__ col,
        const float* __restrict__ a, const float* __restrict__ w,
        int* __restrict__ cursor, uint2* __restrict__ e1,
        const float* __restrict__ x, _Float16* __restrict__ xt) {
    __shared__ unsigned sBuf[256 * 33 / 2 + 8];  // 16.9 KB: h[NBIN] or fp16 tile
    int blk = blockIdx.x, tid = threadIdx.x;

    if (blk >= NBLK1) {                      // ---- fused coalesced transpose ----
        _Float16* tl = (_Float16*)sBuf;      // [256][33] fp16 tile
        int n0 = (blk - NBLK1) * 256;
        int n = n0 + tid;
#pragma unroll 8
        for (int b = 0; b < 32; ++b) {       // coalesced x reads (1KB/wave rows)
            float v = (n < NN) ? x[b * NN + n] : 0.0f;
            tl[tid * 33 + b] = (_Float16)v;
        }
        __syncthreads();
#pragma unroll
        for (int k = 0; k < 4; ++k) {        // coalesced uint4 stores (16B/lane)
            int o = (tid + 256 * k) * 8;     // output offset within tile
            int nl = o >> 5;
            int b0 = o & 31;
            int nn = n0 + nl;
            if (nn < NN) {
                union { uint4 u4; _Float16 hh[8]; } pk;
#pragma unroll
                for (int j = 0; j < 8; ++j) pk.hh[j] = tl[nl * 33 + b0 + j];
                *(uint4*)&xt[nn * 32 + b0] = pk.u4;
            }
        }
        return;
    }

    int* h = (int*)sBuf;                     // NBIN counts -> global slot cursors
    int base = blk * CHUNK;
    int n = NNZ_E - base; if (n > CHUNK) n = CHUNK;   // 3072 or 2560 (both %4==0)
    int nv = n >> 2;

    for (int j = tid; j < NBIN; j += 256) h[j] = 0;
    __syncthreads();

    // vectorized edge loads; edges stay in registers through write-out
    int rr[12], cc[12];
    unsigned aw2[12];
    int ne = 0;
    const int4*   rv4 = (const int4*)row;
    const int4*   cv4 = (const int4*)col;
    const float4* av4 = (const float4*)a;
    const float4* wv4 = (const float4*)w;
    int b4 = base >> 2;
    for (int t4 = tid; t4 < nv; t4 += 256) {
        int4 r = rv4[b4 + t4];
        int4 c = cv4[b4 + t4];
        float4 af = av4[b4 + t4];
        float4 wf = wv4[b4 + t4];
        rr[ne] = r.x; cc[ne] = c.x; aw2[ne] = ((unsigned)f2h(af.x) << 16) | f2h(wf.x); ++ne;
        rr[ne] = r.y; cc[ne] = c.y; aw2[ne] = ((unsigned)f2h(af.y) << 16) | f2h(wf.y); ++ne;
        rr[ne] = r.z; cc[ne] = c.z; aw2[ne] = ((unsigned)f2h(af.z) << 16) | f2h(wf.z); ++ne;
        rr[ne] = r.w; cc[ne] = c.w; aw2[ne] = ((unsigned)f2h(af.w) << 16) | f2h(wf.w); ++ne;
    }
    for (int i = 0; i < ne; ++i)
        atomicAdd(&h[clampi(rr[i], NN - 1) >> 7], 1);
    __syncthreads();

    // claim global window segments (one atomic per nonempty bin);
    // h[j] becomes the bin's global e1 slot cursor
    int j0 = tid * 2, j1 = tid * 2 + 1;
    if (j0 < NBIN) {
        int c0 = h[j0];
        int b0 = c0 ? atomicAdd(&cursor[j0], c0) : 0;
        h[j0] = j0 * BCAP1 + clampi(b0, BCAP1 - 1);
    }
    if (j1 < NBIN) {
        int c1 = h[j1];
        int b1 = c1 ? atomicAdd(&cursor[j1], c1) : 0;
        h[j1] = j1 * BCAP1 + clampi(b1, BCAP1 - 1);
    }
    __syncthreads();

    // direct write-out: one LDS cursor atomic + one 8B store per edge
    for (int i = 0; i < ne; ++i) {
        int r = clampi(rr[i], NN - 1);
        int c = clampi(cc[i], NN - 1);
        int bin = r >> 7;
        int d = atomicAdd(&h[bin], 1);       // global e1 slot
        d = clampi(d, LENE - 1);             // hardening
        e1[d] = make_uint2(((unsigned)r << 16) | (unsigned)c, aw2[i]);
    }
}

// Pass 2: one block per 128-row bin (size from cursor[bin]); no LDS staging:
// loop 1 reads e1 window to histogram rows, loop 2 re-reads (L2-hot) and
// places via per-row LDS cursors. Emits row_desc[r] = start|(niters<<24);
// pads each row to multiple-of-8 kv slots with kv=0.
__global__ __launch_bounds__(256) void pass2_kernel(
        const uint2* __restrict__ e1, const int* __restrict__ cursor,
        unsigned* __restrict__ kvA2, unsigned* __restrict__ kvW2,
        unsigned* __restrict__ row_desc) {
    __shared__ int rh[128];
    __shared__ int rs[128];
    __shared__ int cur[128];
    int bin = blockIdx.x, tid = threadIdx.x;
    int r0 = bin << 7;
    int rows = NN - r0; if (rows > 128) rows = 128;
    int ebase = bin * BCAP1;
    int size = clampi(cursor[bin], CAP2);    // bin fill (cap: hardening)
    int pbase = bin * BCAP;

    if (tid < 128) rh[tid] = 0;
    __syncthreads();
    for (int i = tid; i < size; i += 256)
        atomicAdd(&rh[(e1[ebase + i].x >> 16) & 127], 1);
    __syncthreads();
    int cnt  = (tid < 128) ? rh[tid] : 0;
    int plen = (cnt + 7) & ~7;
    if (tid < 128) rs[tid] = plen;
    __syncthreads();
    for (int off = 1; off < 128; off <<= 1) {
        int t = (tid >= off && tid < 128) ? rs[tid - off] : 0;
        __syncthreads();
        if (tid < 128) rs[tid] += t;
        __syncthreads();
    }
    int rofs = (tid < 128) ? clampi(rs[tid] - plen, BCAP - 8) : 0;
    if (tid < 128) cur[tid] = rofs;
    if (tid < rows)
        row_desc[r0 + tid] = (unsigned)(pbase + rofs) | ((unsigned)(plen >> 3) << 24);
    __syncthreads();
    for (int i = tid; i < size; i += 256) {
        uint2 e = e1[ebase + i];             // L2-hot re-read (8B coalesced)
        unsigned key = e.x;
        unsigned aw  = e.y;
        int rl = (key >> 16) & 127;
        int p = atomicAdd(&cur[rl], 1);
        p = clampi(p, BCAP - 1);             // hardening
        unsigned c = key & 0xFFFFu;
        kvA2[pbase + p] = (aw & 0xFFFF0000u) | c;
        kvW2[pbase + p] = (aw << 16) | c;
    }
    __syncthreads();
    if (tid < rows) {
        int pl = (rh[tid] + 7) & ~7;
        for (int q = rh[tid]; q < pl; ++q) {
            int d = clampi(rofs + q, BCAP - 1);
            kvA2[pbase + d] = 0u;
            kvW2[pbase + d] = 0u;
        }
    }
}

// 16 lanes per row; lane l owns batch pair (2l, 2l+1) as one fp16x2 dword.
// 4 rows per wave64 (r15/r20 structure: uniform counted loop over rows
// padded to multiple-of-8 edges, uint2 kv loads, depth-1 kv prefetch, fp32
// accumulation, packed dword store).
// FINAL=1 (last A-pass): writes fp32 out[b*NN+r] = result * 2^24 directly
// (fused transpose_out; skips the intermediate fp16 rounding).
template <int WITH_BIAS, int FINAL>
__global__ __launch_bounds__(256) void spmm_kernel(
        const uint2* __restrict__ kv2, const unsigned* __restrict__ row_desc,
        const unsigned* __restrict__ in32, unsigned* __restrict__ out32,
        const float* __restrict__ bias, float outScale, float biasScale,
        float* __restrict__ outf) {
    int t = blockIdx.x * 256 + threadIdx.x;
    int r = t >> 4;                          // one row per 16 lanes
    int l = t & 15;                          // batch-pair index
    if (r >= NN) return;
    unsigned d = row_desc[r];
    int niter = (int)(d >> 24);
    int base2 = clampi((int)(d & 0xFFFFFFu), LENP - 8) >> 1;  // 8-slot aligned
    float accL = 0.0f, accH = 0.0f;          // batch 2l, 2l+1
    uint2 k2[4];
    if (niter > 0) {
#pragma unroll
        for (int q = 0; q < 4; ++q) k2[q] = kv2[base2 + q];
    }
    for (int it = 0; it < niter; ++it) {
        unsigned k[8];
#pragma unroll
        for (int q = 0; q < 4; ++q) { k[2 * q] = k2[q].x; k[2 * q + 1] = k2[q].y; }
        unsigned gd[8];
#pragma unroll
        for (int j = 0; j < 8; ++j) gd[j] = in32[((k[j] & 0xFFFFu) << 4) + l];
        if (it + 1 < niter) {
            int nb2 = base2 + (it + 1) * 4;
#pragma unroll
            for (int q = 0; q < 4; ++q) k2[q] = kv2[nb2 + q];
        }
#pragma unroll
        for (int j = 0; j < 8; ++j) {
            float v = kv_val(k[j]);
            union { unsigned u; _Float16 h[2]; } cv;
            cv.u = gd[j];
            accL += v * (float)cv.h[0];
            accH += v * (float)cv.h[1];
        }
    }
    float rL = accL * outScale, rH = accH * outScale;
    if (WITH_BIAS) {
        float bb = bias[r] * biasScale;
        rL += bb; rH += bb;
    }
    if (FINAL) {
        // fused transpose_out: undo cumulative 256^-3 state scaling (x 2^24)
        outf[(2 * l) * NN + r]     = rL * 16777216.0f;
        outf[(2 * l + 1) * NN + r] = rH * 16777216.0f;
    } else {
        union { unsigned u; _Float16 h[2]; } o;
        o.h[0] = (_Float16)rL;
        o.h[1] = (_Float16)rH;
        out32[(r << 4) + l] = o.u;
    }
}

extern "C" void kernel_launch(void* const* d_in, const int* in_sizes, int n_in,
                              void* d_out, int out_size, void* d_ws, size_t ws_size,
                              hipStream_t stream) {
    const float* x        = (const float*)d_in[0];
    const float* adj_vals = (const float*)d_in[1];
    const float* w_vals   = (const float*)d_in[2];
    const float* bias     = (const float*)d_in[3];
    const int*   row      = (const int*)d_in[4];
    const int*   col      = (const int*)d_in[5];
    float* out = (float*)d_out;

    // Workspace (~45 MB of the 256 MiB ws)
    uint2*     e1        = (uint2*)d_ws;             // LENE windowed {key, aw}
    unsigned*  kvA2      = (unsigned*)(e1 + LENE);   // LENP padded kv (A)
    unsigned*  kvW2      = kvA2 + LENP;              // LENP padded kv (W)
    _Float16*  xt16      = (_Float16*)(kvW2 + LENP); // NB fp16
    _Float16*  tmp16     = xt16 + NB;                // NB fp16
    int*       cursor    = (int*)(tmp16 + NB);       // NBIN bin-fill cursors
    unsigned*  row_desc  = (unsigned*)(cursor + NBIN + 8);  // NN

    const int BS = 256;
    const int grid_spmm = (NN * 16 + BS - 1) / BS;   // 3125

    // ---- single-pass bin grouping (cursor-claimed fixed windows) ----
    hipMemsetAsync(cursor, 0, NBIN * sizeof(int), stream);
    pass1_kernel<<<NBLK1 + TIN_BLKS, BS, 0, stream>>>(row, col, adj_vals, w_vals,
                                                      cursor, e1, x, xt16);
    pass2_kernel<<<NBIN, BS, 0, stream>>>(e1, cursor, kvA2, kvW2, row_desc);

    const uint2* kvA = (const uint2*)kvA2;
    const uint2* kvW = (const uint2*)kvW2;
    const unsigned* xt32  = (const unsigned*)xt16;
    unsigned*       xt32w = (unsigned*)xt16;
    const unsigned* tm32  = (const unsigned*)tmp16;
    unsigned*       tm32w = (unsigned*)tmp16;

    // ---- dense passes (scaled fp16 state: state_l = xt_l * 256^-l) ----
    const float r256 = 1.0f / 256.0f;
    spmm_kernel<0, 0><<<grid_spmm, BS, 0, stream>>>(kvW, row_desc, xt32, tm32w,
                                                    nullptr, 1.0f, 0.0f, nullptr);
    spmm_kernel<1, 0><<<grid_spmm, BS, 0, stream>>>(kvA, row_desc, tm32, xt32w,
                                                    bias, r256, 1.0f / 256.0f, nullptr);
    spmm_kernel<0, 0><<<grid_spmm, BS, 0, stream>>>(kvW, row_desc, xt32, tm32w,
                                                    nullptr, 1.0f, 0.0f, nullptr);
    spmm_kernel<1, 0><<<grid_spmm, BS, 0, stream>>>(kvA, row_desc, tm32, xt32w,
                                                    bias, r256, 1.0f / 65536.0f, nullptr);
    spmm_kernel<0, 0><<<grid_spmm, BS, 0, stream>>>(kvW, row_desc, xt32, tm32w,
                                                    nullptr, 1.0f, 0.0f, nullptr);
    spmm_kernel<1, 1><<<grid_spmm, BS, 0, stream>>>(kvA, row_desc, tm32, xt32w,
                                                    bias, r256, 1.0f / 16777216.0f, out);
}

// Round 13
// 237.749 us; speedup vs baseline: 1.0009x; 1.0009x over previous
//
#include <hip/hip_runtime.h>

// AdultConnectomeNetwork: 3 layers of xt = A_sp @ (W_sp @ xt) + bias.
// Round 28: pass1 scheduling + parallelism. r27 showed pass1 (~48us) is
// neither traffic- nor chain-bound: it is (a) grid-starved (717 blocks,
// ~2.8/CU) and (b) tail-serialized (the 196 fused transpose blocks have the
// HIGHEST blockIdx values -> run as a ~10us tail after the sort blocks).
//  1. Transpose blocks FIRST (blk < TIN_BLKS): overlap instead of tail.
//  2. Claim-window granularity decoupled from kv-bin granularity: e1 windows
//     are 256-row (196 windows) so CHUNK drops 3072 -> 1536 (1042 sort
//     blocks, 2x parallelism) while per-(block,window) segments stay
//     1536/196 ~ 7.8 edges ~ 63B (r22/r23 density law satisfied).
//     pass2 keeps 128-row kv bins: 2 blocks per window, each filters its
//     half on the L2-hot re-read.
//  - De-staged pass1 writes (r27), de-staged pass2 (r24), r20 spmm, scaled
//    fp16 state, fused transposes: unchanged.
// Hardening: computed indices clamped (logic error -> absmax fail, not fault).

#define NN 50000
#define NNZ_E 1600000
#define NB (NN * 32)
#define CHUNK 1536
#define NBLK1 ((NNZ_E + CHUNK - 1) / CHUNK)      // 1042
#define NWIN ((NN + 255) / 256)                  // 196 claim windows (256 rows)
#define NBIN ((NN + 127) / 128)                  // 391 kv bins (128 rows)
#define CAP2W 10240                              // window fill cap (mean 8163, +23 sigma)
#define BCAP1W 12288                             // e1 slots per window
#define LENE (NWIN * BCAP1W)                     // 2408448 e1 slots (19.3 MB)
#define CAP2 5120                                // kv-bin edge cap (hardening)
#define BCAP 6144                                // padded kv capacity per 128-row bin
#define LENP (NBIN * BCAP)                       // 2402304 padded kv slots
#define TIN_BLKS 196                             // transpose tiles of 256 n (FIRST)

__device__ __forceinline__ int clampi(int v, int hi) {  // [0, hi]
    v = v < 0 ? 0 : v;
    return v > hi ? hi : v;
}

__device__ __forceinline__ unsigned short f2h(float v) {
    union { _Float16 h; unsigned short u; } cv;
    cv.h = (_Float16)v;
    return cv.u;
}

__device__ __forceinline__ float kv_val(unsigned kv) {
    union { unsigned short u; _Float16 h; } cv;
    cv.u = (unsigned short)(kv >> 16);
    return (float)cv.h;
}

// Pass 1 (de-staged, window-claimed): blocks < TIN_BLKS run the LDS-tiled
// coalesced input transpose (SCHEDULED FIRST to overlap the sort blocks);
// remaining 1042 blocks: hist over 196 windows -> claim global segment per
// nonempty window (h[] becomes global e1 slot cursor) -> direct 8B writes.
// key = (row<<16)|col.
__global__ __launch_bounds__(256) void pass1_kernel(
        const int* __restrict__ row, const int* __restrict__ col,
        const float* __restrict__ a, const float* __restrict__ w,
        int* __restrict__ cursor, uint2* __restrict__ e1,
        const float* __restrict__ x, _Float16* __restrict__ xt) {
    __shared__ unsigned sBuf[256 * 33 / 2 + 8];  // 16.9 KB: tile or h[NWIN]
    int blk = blockIdx.x, tid = threadIdx.x;

    if (blk < TIN_BLKS) {                    // ---- fused coalesced transpose ----
        _Float16* tl = (_Float16*)sBuf;      // [256][33] fp16 tile
        int n0 = blk * 256;
        int n = n0 + tid;
#pragma unroll 8
        for (int b = 0; b < 32; ++b) {       // coalesced x reads (1KB/wave rows)
            float v = (n < NN) ? x[b * NN + n] : 0.0f;
            tl[tid * 33 + b] = (_Float16)v;
        }
        __syncthreads();
#pragma unroll
        for (int k = 0; k < 4; ++k) {        // coalesced uint4 stores (16B/lane)
            int o = (tid + 256 * k) * 8;     // output offset within tile
            int nl = o >> 5;
            int b0 = o & 31;
            int nn = n0 + nl;
            if (nn < NN) {
                union { uint4 u4; _Float16 hh[8]; } pk;
#pragma unroll
                for (int j = 0; j < 8; ++j) pk.hh[j] = tl[nl * 33 + b0 + j];
                *(uint4*)&xt[nn * 32 + b0] = pk.u4;
            }
        }
        return;
    }

    int* h = (int*)sBuf;                     // NWIN counts -> global slot cursors
    int base = (blk - TIN_BLKS) * CHUNK;
    int n = NNZ_E - base; if (n > CHUNK) n = CHUNK;   // 1536 or 1024 (both %4==0)
    int nv = n >> 2;

    for (int j = tid; j < NWIN; j += 256) h[j] = 0;
    __syncthreads();

    // vectorized edge loads; edges stay in registers through write-out
    int rr[8], cc[8];
    unsigned aw2[8];
    int ne = 0;
    const int4*   rv4 = (const int4*)row;
    const int4*   cv4 = (const int4*)col;
    const float4* av4 = (const float4*)a;
    const float4* wv4 = (const float4*)w;
    int b4 = base >> 2;
    for (int t4 = tid; t4 < nv; t4 += 256) {
        int4 r = rv4[b4 + t4];
        int4 c = cv4[b4 + t4];
        float4 af = av4[b4 + t4];
        float4 wf = wv4[b4 + t4];
        rr[ne] = r.x; cc[ne] = c.x; aw2[ne] = ((unsigned)f2h(af.x) << 16) | f2h(wf.x); ++ne;
        rr[ne] = r.y; cc[ne] = c.y; aw2[ne] = ((unsigned)f2h(af.y) << 16) | f2h(wf.y); ++ne;
        rr[ne] = r.z; cc[ne] = c.z; aw2[ne] = ((unsigned)f2h(af.z) << 16) | f2h(wf.z); ++ne;
        rr[ne] = r.w; cc[ne] = c.w; aw2[ne] = ((unsigned)f2h(af.w) << 16) | f2h(wf.w); ++ne;
    }
    for (int i = 0; i < ne; ++i)
        atomicAdd(&h[clampi(rr[i], NN - 1) >> 8], 1);
    __syncthreads();

    // claim global window segments (one atomic per nonempty window);
    // h[j] becomes the window's global e1 slot cursor
    if (tid < NWIN) {
        int c0 = h[tid];
        int b0 = c0 ? atomicAdd(&cursor[tid], c0) : 0;
        h[tid] = tid * BCAP1W + clampi(b0, BCAP1W - 1);
    }
    __syncthreads();

    // direct write-out: one LDS cursor atomic + one 8B store per edge
    for (int i = 0; i < ne; ++i) {
        int r = clampi(rr[i], NN - 1);
        int c = clampi(cc[i], NN - 1);
        int wb = r >> 8;
        int d = atomicAdd(&h[wb], 1);        // global e1 slot
        d = clampi(d, LENE - 1);             // hardening
        e1[d] = make_uint2(((unsigned)r << 16) | (unsigned)c, aw2[i]);
    }
}

// Pass 2: TWO blocks per 256-row window; block handles 128-row half
// (bin = blockIdx, window = bin>>1). Loop 1 reads the window, histograms
// only rows in its half; loop 2 re-reads (L2-hot) and places via per-row
// LDS cursors. Emits row_desc[r] = start|(niters<<24); pads each row to
// multiple-of-8 kv slots with kv=0.
__global__ __launch_bounds__(256) void pass2_kernel(
        const uint2* __restrict__ e1, const int* __restrict__ cursor,
        unsigned* __restrict__ kvA2, unsigned* __restrict__ kvW2,
        unsigned* __restrict__ row_desc) {
    __shared__ int rh[128];
    __shared__ int rs[128];
    __shared__ int cur[128];
    int bin = blockIdx.x, tid = threadIdx.x;
    int r0 = bin << 7;
    int rows = NN - r0; if (rows > 128) rows = 128;
    int win = bin >> 1;
    int ebase = win * BCAP1W;
    int size = clampi(cursor[win], CAP2W);   // window fill (cap: hardening)
    int pbase = bin * BCAP;

    if (tid < 128) rh[tid] = 0;
    __syncthreads();
    for (int i = tid; i < size; i += 256) {
        int rr = (int)(e1[ebase + i].x >> 16);
        if ((rr >> 7) == bin) atomicAdd(&rh[rr & 127], 1);
    }
    __syncthreads();
    int cnt  = (tid < 128) ? clampi(rh[tid], CAP2) : 0;
    int plen = (cnt + 7) & ~7;
    if (tid < 128) rs[tid] = plen;
    __syncthreads();
    for (int off = 1; off < 128; off <<= 1) {
        int t = (tid >= off && tid < 128) ? rs[tid - off] : 0;
        __syncthreads();
        if (tid < 128) rs[tid] += t;
        __syncthreads();
    }
    int rofs = (tid < 128) ? clampi(rs[tid] - plen, BCAP - 8) : 0;
    if (tid < 128) cur[tid] = rofs;
    if (tid < rows)
        row_desc[r0 + tid] = (unsigned)(pbase + rofs) | ((unsigned)(plen >> 3) << 24);
    __syncthreads();
    for (int i = tid; i < size; i += 256) {
        uint2 e = e1[ebase + i];             // L2-hot re-read (8B coalesced)
        unsigned key = e.x;
        int rr = (int)(key >> 16);
        if ((rr >> 7) != bin) continue;
        unsigned aw = e.y;
        int p = atomicAdd(&cur[rr & 127], 1);
        p = clampi(p, BCAP - 1);             // hardening
        unsigned c = key & 0xFFFFu;
        kvA2[pbase + p] = (aw & 0xFFFF0000u) | c;
        kvW2[pbase + p] = (aw << 16) | c;
    }
    __syncthreads();
    if (tid < rows) {
        int cnt2 = clampi(rh[tid], CAP2);
        int pl = (cnt2 + 7) & ~7;
        for (int q = cnt2; q < pl; ++q) {
            int d = clampi(rofs + q, BCAP - 1);
            kvA2[pbase + d] = 0u;
            kvW2[pbase + d] = 0u;
        }
    }
}

// 16 lanes per row; lane l owns batch pair (2l, 2l+1) as one fp16x2 dword.
// 4 rows per wave64 (r15/r20 structure: uniform counted loop over rows
// padded to multiple-of-8 edges, uint2 kv loads, depth-1 kv prefetch, fp32
// accumulation, packed dword store).
// FINAL=1 (last A-pass): writes fp32 out[b*NN+r] = result * 2^24 directly
// (fused transpose_out; skips the intermediate fp16 rounding).
template <int WITH_BIAS, int FINAL>
__global__ __launch_bounds__(256) void spmm_kernel(
        const uint2* __restrict__ kv2, const unsigned* __restrict__ row_desc,
        const unsigned* __restrict__ in32, unsigned* __restrict__ out32,
        const float* __restrict__ bias, float outScale, float biasScale,
        float* __restrict__ outf) {
    int t = blockIdx.x * 256 + threadIdx.x;
    int r = t >> 4;                          // one row per 16 lanes
    int l = t & 15;                          // batch-pair index
    if (r >= NN) return;
    unsigned d = row_desc[r];
    int niter = (int)(d >> 24);
    int base2 = clampi((int)(d & 0xFFFFFFu), LENP - 8) >> 1;  // 8-slot aligned
    float accL = 0.0f, accH = 0.0f;          // batch 2l, 2l+1
    uint2 k2[4];
    if (niter > 0) {
#pragma unroll
        for (int q = 0; q < 4; ++q) k2[q] = kv2[base2 + q];
    }
    for (int it = 0; it < niter; ++it) {
        unsigned k[8];
#pragma unroll
        for (int q = 0; q < 4; ++q) { k[2 * q] = k2[q].x; k[2 * q + 1] = k2[q].y; }
        unsigned gd[8];
#pragma unroll
        for (int j = 0; j < 8; ++j) gd[j] = in32[((k[j] & 0xFFFFu) << 4) + l];
        if (it + 1 < niter) {
            int nb2 = base2 + (it + 1) * 4;
#pragma unroll
            for (int q = 0; q < 4; ++q) k2[q] = kv2[nb2 + q];
        }
#pragma unroll
        for (int j = 0; j < 8; ++j) {
            float v = kv_val(k[j]);
            union { unsigned u; _Float16 h[2]; } cv;
            cv.u = gd[j];
            accL += v * (float)cv.h[0];
            accH += v * (float)cv.h[1];
        }
    }
    float rL = accL * outScale, rH = accH * outScale;
    if (WITH_BIAS) {
        float bb = bias[r] * biasScale;
        rL += bb; rH += bb;
    }
    if (FINAL) {
        // fused transpose_out: undo cumulative 256^-3 state scaling (x 2^24)
        outf[(2 * l) * NN + r]     = rL * 16777216.0f;
        outf[(2 * l + 1) * NN + r] = rH * 16777216.0f;
    } else {
        union { unsigned u; _Float16 h[2]; } o;
        o.h[0] = (_Float16)rL;
        o.h[1] = (_Float16)rH;
        out32[(r << 4) + l] = o.u;
    }
}

extern "C" void kernel_launch(void* const* d_in, const int* in_sizes, int n_in,
                              void* d_out, int out_size, void* d_ws, size_t ws_size,
                              hipStream_t stream) {
    const float* x        = (const float*)d_in[0];
    const float* adj_vals = (const float*)d_in[1];
    const float* w_vals   = (const float*)d_in[2];
    const float* bias     = (const float*)d_in[3];
    const int*   row      = (const int*)d_in[4];
    const int*   col      = (const int*)d_in[5];
    float* out = (float*)d_out;

    // Workspace (~45 MB of the 256 MiB ws)
    uint2*     e1        = (uint2*)d_ws;             // LENE windowed {key, aw}
    unsigned*  kvA2      = (unsigned*)(e1 + LENE);   // LENP padded kv (A)
    unsigned*  kvW2      = kvA2 + LENP;              // LENP padded kv (W)
    _Float16*  xt16      = (_Float16*)(kvW2 + LENP); // NB fp16
    _Float16*  tmp16     = xt16 + NB;                // NB fp16
    int*       cursor    = (int*)(tmp16 + NB);       // NWIN window-fill cursors
    unsigned*  row_desc  = (unsigned*)(cursor + NWIN + 8);  // NN

    const int BS = 256;
    const int grid_spmm = (NN * 16 + BS - 1) / BS;   // 3125

    // ---- single-pass window grouping (cursor-claimed fixed windows) ----
    hipMemsetAsync(cursor, 0, NWIN * sizeof(int), stream);
    pass1_kernel<<<TIN_BLKS + NBLK1, BS, 0, stream>>>(row, col, adj_vals, w_vals,
                                                      cursor, e1, x, xt16);
    pass2_kernel<<<NBIN, BS, 0, stream>>>(e1, cursor, kvA2, kvW2, row_desc);

    const uint2* kvA = (const uint2*)kvA2;
    const uint2* kvW = (const uint2*)kvW2;
    const unsigned* xt32  = (const unsigned*)xt16;
    unsigned*       xt32w = (unsigned*)xt16;
    const unsigned* tm32  = (const unsigned*)tmp16;
    unsigned*       tm32w = (unsigned*)tmp16;

    // ---- dense passes (scaled fp16 state: state_l = xt_l * 256^-l) ----
    const float r256 = 1.0f / 256.0f;
    spmm_kernel<0, 0><<<grid_spmm, BS, 0, stream>>>(kvW, row_desc, xt32, tm32w,
                                                    nullptr, 1.0f, 0.0f, nullptr);
    spmm_kernel<1, 0><<<grid_spmm, BS, 0, stream>>>(kvA, row_desc, tm32, xt32w,
                                                    bias, r256, 1.0f / 256.0f, nullptr);
    spmm_kernel<0, 0><<<grid_spmm, BS, 0, stream>>>(kvW, row_desc, xt32, tm32w,
                                                    nullptr, 1.0f, 0.0f, nullptr);
    spmm_kernel<1, 0><<<grid_spmm, BS, 0, stream>>>(kvA, row_desc, tm32, xt32w,
                                                    bias, r256, 1.0f / 65536.0f, nullptr);
    spmm_kernel<0, 0><<<grid_spmm, BS, 0, stream>>>(kvW, row_desc, xt32, tm32w,
                                                    nullptr, 1.0f, 0.0f, nullptr);
    spmm_kernel<1, 1><<<grid_spmm, BS, 0, stream>>>(kvA, row_desc, tm32, xt32w,
                                                    bias, r256, 1.0f / 16777216.0f, out);
}